// Round 5
// baseline (15721.289 us; speedup 1.0000x reference)
//
#include <hip/hip_runtime.h>
#include <math.h>

// Problem constants (from reference)
constexpr int CB = 4;
constexpr int CE = 1536;
constexpr int CR = 512;
constexpr int CN = 2048;          // E + R
constexpr int CHS = 512;          // HSZ
constexpr int CNH = 4;            // heads
constexpr int CDK = 128;          // head dim
constexpr int CM = CB * CN;       // 8192 rows
constexpr float CNEG = -1000000000.0f;

// ---------------------------------------------------------------------------
// vg = concat(vents, renc_w[rels]) : (B, N, 512)
// ---------------------------------------------------------------------------
__global__ __launch_bounds__(256) void build_vg_kernel(
    const float* __restrict__ vents, const float* __restrict__ renc,
    const int* __restrict__ rels, float* __restrict__ vg)
{
    int i = blockIdx.x * 256 + threadIdx.x;      // float4 index, 1,048,576 total
    int row = i >> 7;                            // / (512/4)
    int c4 = i & 127;
    int b = row / CN;
    int n = row % CN;
    const float4* src;
    if (n < CE) {
        src = reinterpret_cast<const float4*>(vents + ((size_t)b * CE + n) * CHS);
    } else {
        int r = rels[b * CR + (n - CE)];
        src = reinterpret_cast<const float4*>(renc + (size_t)r * CHS);
    }
    reinterpret_cast<float4*>(vg)[(size_t)row * 128 + c4] = src[c4];
}

// ---------------------------------------------------------------------------
// C = A(M,K) @ W(K,Nc) + bias [+ PReLU(col)]  — fp32 tiled, 128x64 tile
// ---------------------------------------------------------------------------
#define GBM 128
#define GBN 64
#define GBK 16

__global__ __launch_bounds__(256) void gemm_bias_kernel(
    const float* __restrict__ A, const float* __restrict__ W,
    const float* __restrict__ bias, const float* __restrict__ prelu,
    float* __restrict__ C, int K, int Nc)
{
    __shared__ float As[GBK][GBM + 4];
    __shared__ float Bs[GBK][GBN + 4];
    const int tid = threadIdx.x;
    const int bm = blockIdx.y * GBM;
    const int bn = blockIdx.x * GBN;
    const int tx = tid & 15;
    const int ty = tid >> 4;

    float acc[8][4];
#pragma unroll
    for (int i = 0; i < 8; ++i)
#pragma unroll
        for (int j = 0; j < 4; ++j) acc[i][j] = 0.f;

    for (int k0 = 0; k0 < K; k0 += GBK) {
        // A tile 128x16 (stored transposed), 2 float4 per thread
#pragma unroll
        for (int l = 0; l < 2; ++l) {
            int idx = tid + l * 256;
            int r = idx >> 2;
            int c = (idx & 3) << 2;
            float4 av = *reinterpret_cast<const float4*>(A + (size_t)(bm + r) * K + k0 + c);
            As[c + 0][r] = av.x; As[c + 1][r] = av.y;
            As[c + 2][r] = av.z; As[c + 3][r] = av.w;
        }
        // B tile 16x64, 1 float4 per thread
        {
            int r = tid >> 4;
            int c = (tid & 15) << 2;
            float4 bv = *reinterpret_cast<const float4*>(W + (size_t)(k0 + r) * Nc + bn + c);
            Bs[r][c + 0] = bv.x; Bs[r][c + 1] = bv.y;
            Bs[r][c + 2] = bv.z; Bs[r][c + 3] = bv.w;
        }
        __syncthreads();
#pragma unroll
        for (int kk = 0; kk < GBK; ++kk) {
            float a[8], b[4];
#pragma unroll
            for (int i = 0; i < 8; ++i) a[i] = As[kk][ty * 8 + i];
#pragma unroll
            for (int j = 0; j < 4; ++j) b[j] = Bs[kk][tx * 4 + j];
#pragma unroll
            for (int i = 0; i < 8; ++i)
#pragma unroll
                for (int j = 0; j < 4; ++j)
                    acc[i][j] = fmaf(a[i], b[j], acc[i][j]);
        }
        __syncthreads();
    }

    float bv[4], al[4];
#pragma unroll
    for (int j = 0; j < 4; ++j) bv[j] = bias[bn + tx * 4 + j];
    if (prelu) {
#pragma unroll
        for (int j = 0; j < 4; ++j) al[j] = prelu[bn + tx * 4 + j];
    }
#pragma unroll
    for (int i = 0; i < 8; ++i) {
        float4 o;
        float* po = &o.x;
#pragma unroll
        for (int j = 0; j < 4; ++j) {
            float vv = acc[i][j] + bv[j];
            if (prelu) vv = vv > 0.f ? vv : al[j] * vv;   // max(v,0)+a*min(v,0)
            po[j] = vv;
        }
        *reinterpret_cast<float4*>(C + (size_t)(bm + ty * 8 + i) * Nc + bn + tx * 4) = o;
    }
}

// ---------------------------------------------------------------------------
// Flash attention with adjacency mask. One wg per (b, h, 128-row Q block).
// 512 threads. S micro 4x4 (ty=tid>>4 in 0..31, tx=tid&15), O micro 4x8.
// LDS ≈ 134.8 KB (< 160 KB gfx950 limit) -> 1 block/CU = 8 waves = 2/SIMD.
// __launch_bounds__(512, 2): tell the allocator the TRUE occupancy target
// so it uses the full 256-VGPR budget instead of capping at 128 and
// spilling the PV operand arrays to scratch (R2: 13.6 GB of scratch writes
// per dispatch made attn memory-bound at 3.3 TB/s, 6.9 ms each).
// KVS_LD = 133 (odd): QK^T reads KVs[tx*4+j][kk] — 16 rows/wave. With row
// stride 132 (132%32==4) those rows hit only 2 banks (8-way conflict,
// R2: 1.34e8 SQ_LDS_BANK_CONFLICT). Odd stride -> 4*133%32==20,
// gcd(20,32)=4 -> 8 banks, 2 rows/bank = minimal (free per m136).
// ---------------------------------------------------------------------------
#define ABQ 128
#define ACH 64
#define KVS_LD (CDK + 5)   // 133, odd — see note above

__global__ __launch_bounds__(512, 2) void attn_kernel(
    const float* __restrict__ q, const float* __restrict__ k,
    const float* __restrict__ v, const int* __restrict__ adj,
    float* __restrict__ o)
{
    __shared__ float Qs[ABQ][CDK + 4];   // 67.6 KB
    __shared__ float KVs[ACH][KVS_LD];   // 34.0 KB (K then V)
    __shared__ float Ps[ABQ][ACH + 4];   // 34.8 KB
    __shared__ float m_s[ABQ], l_s[ABQ], a_s[ABQ];

    const int tid = threadIdx.x;
    const int b = blockIdx.z, h = blockIdx.y;
    const int q0 = blockIdx.x * ABQ;
    const int tx = tid & 15;
    const int ty = tid >> 4;             // 0..31
    const float scale = 0.08838834764831845f;   // 1/sqrt(128)

    // load Q tile (128 x 128)
    const float* qbase = q + ((size_t)(b * CN + q0)) * CHS + h * CDK;
#pragma unroll
    for (int l = 0; l < 8; ++l) {
        int idx = tid + l * 512;
        int r = idx >> 5;
        int c = (idx & 31) << 2;
        *reinterpret_cast<float4*>(&Qs[r][c]) =
            *reinterpret_cast<const float4*>(qbase + (size_t)r * CHS + c);
    }
    if (tid < ABQ) { m_s[tid] = -INFINITY; l_s[tid] = 0.f; }

    float acc[4][8];
#pragma unroll
    for (int i = 0; i < 4; ++i)
#pragma unroll
        for (int j = 0; j < 8; ++j) acc[i][j] = 0.f;
    __syncthreads();

    for (int k0 = 0; k0 < CN; k0 += ACH) {
        // load K chunk (64 x 128)
        const float* kbase = k + ((size_t)(b * CN + k0)) * CHS + h * CDK;
#pragma unroll
        for (int l = 0; l < 4; ++l) {
            int idx = tid + l * 512;
            int r = idx >> 5;
            int c = (idx & 31) << 2;
            *reinterpret_cast<float4*>(&KVs[r][c]) =
                *reinterpret_cast<const float4*>(kbase + (size_t)r * CHS + c);
        }
        __syncthreads();

        // S = Q K^T (4x4 per thread)
        float s[4][4];
#pragma unroll
        for (int i = 0; i < 4; ++i)
#pragma unroll
            for (int j = 0; j < 4; ++j) s[i][j] = 0.f;
#pragma unroll
        for (int kk = 0; kk < CDK; kk += 4) {
            float4 a4[4], b4[4];
#pragma unroll
            for (int i = 0; i < 4; ++i)
                a4[i] = *reinterpret_cast<const float4*>(&Qs[ty * 4 + i][kk]);
#pragma unroll
            for (int j = 0; j < 4; ++j)
                b4[j] = *reinterpret_cast<const float4*>(&KVs[tx * 4 + j][kk]);
#pragma unroll
            for (int i = 0; i < 4; ++i)
#pragma unroll
                for (int j = 0; j < 4; ++j) {
                    s[i][j] = fmaf(a4[i].x, b4[j].x, s[i][j]);
                    s[i][j] = fmaf(a4[i].y, b4[j].y, s[i][j]);
                    s[i][j] = fmaf(a4[i].z, b4[j].z, s[i][j]);
                    s[i][j] = fmaf(a4[i].w, b4[j].w, s[i][j]);
                }
        }

        // mask + scale  (reference: scale first, then mask — equivalent here)
#pragma unroll
        for (int i = 0; i < 4; ++i) {
            int4 av = *reinterpret_cast<const int4*>(
                adj + ((size_t)b * CN + q0 + ty * 4 + i) * CN + k0 + tx * 4);
            const int* ap = &av.x;
#pragma unroll
            for (int j = 0; j < 4; ++j)
                s[i][j] = (ap[j] == 0) ? CNEG : s[i][j] * scale;
        }

        // per-row chunk max over 64 cols (16 lanes x 4 each)
        float rmax[4];
#pragma unroll
        for (int i = 0; i < 4; ++i)
            rmax[i] = fmaxf(fmaxf(s[i][0], s[i][1]), fmaxf(s[i][2], s[i][3]));
#pragma unroll
        for (int off = 1; off < 16; off <<= 1)
#pragma unroll
            for (int i = 0; i < 4; ++i)
                rmax[i] = fmaxf(rmax[i], __shfl_xor(rmax[i], off, 16));

        // NOTE: rows are owned by a 16-lane group entirely inside one wave,
        // so the read-modify-write of m_s/l_s below is wave-lockstep-safe.
        float mold[4], mnew[4], alpha[4], rsum[4];
#pragma unroll
        for (int i = 0; i < 4; ++i) {
            mold[i] = m_s[ty * 4 + i];
            mnew[i] = fmaxf(mold[i], rmax[i]);
            alpha[i] = __expf(mold[i] - mnew[i]);
            rsum[i] = 0.f;
        }
        // P = exp(S - mnew), write to LDS, accumulate row sums
#pragma unroll
        for (int i = 0; i < 4; ++i) {
            float4 p4;
            float* pp = &p4.x;
#pragma unroll
            for (int j = 0; j < 4; ++j) {
                float p = __expf(s[i][j] - mnew[i]);
                pp[j] = p;
                rsum[i] += p;
            }
            *reinterpret_cast<float4*>(&Ps[ty * 4 + i][tx * 4]) = p4;
        }
#pragma unroll
        for (int off = 1; off < 16; off <<= 1)
#pragma unroll
            for (int i = 0; i < 4; ++i)
                rsum[i] += __shfl_xor(rsum[i], off, 16);
        if (tx == 0) {
#pragma unroll
            for (int i = 0; i < 4; ++i) {
                int r = ty * 4 + i;
                l_s[r] = l_s[r] * alpha[i] + rsum[i];
                m_s[r] = mnew[i];
                a_s[r] = alpha[i];
            }
        }
        __syncthreads();   // S/P done; safe to overwrite KVs, Ps visible

        // load V chunk (64 x 128) into KVs
        const float* vbase = v + ((size_t)(b * CN + k0)) * CHS + h * CDK;
#pragma unroll
        for (int l = 0; l < 4; ++l) {
            int idx = tid + l * 512;
            int r = idx >> 5;
            int c = (idx & 31) << 2;
            *reinterpret_cast<float4*>(&KVs[r][c]) =
                *reinterpret_cast<const float4*>(vbase + (size_t)r * CHS + c);
        }
        __syncthreads();

        // O = O*alpha + P @ V   (rows ty*4.., cols tx*8..)
        float alv[4];
#pragma unroll
        for (int i = 0; i < 4; ++i) alv[i] = a_s[ty * 4 + i];
#pragma unroll
        for (int i = 0; i < 4; ++i)
#pragma unroll
            for (int j = 0; j < 8; ++j) acc[i][j] *= alv[i];

#pragma unroll
        for (int m = 0; m < ACH; m += 4) {
            float4 p4[4];
#pragma unroll
            for (int i = 0; i < 4; ++i)
                p4[i] = *reinterpret_cast<const float4*>(&Ps[ty * 4 + i][m]);
            float4 v0[4], v1[4];
#pragma unroll
            for (int mm = 0; mm < 4; ++mm) {
                v0[mm] = *reinterpret_cast<const float4*>(&KVs[m + mm][tx * 8]);
                v1[mm] = *reinterpret_cast<const float4*>(&KVs[m + mm][tx * 8 + 4]);
            }
#pragma unroll
            for (int i = 0; i < 4; ++i) {
                const float* pp = &p4[i].x;
#pragma unroll
                for (int mm = 0; mm < 4; ++mm) {
                    float pv = pp[mm];
                    const float* va = &v0[mm].x;
                    const float* vb = &v1[mm].x;
#pragma unroll
                    for (int j = 0; j < 4; ++j) {
                        acc[i][j]     = fmaf(pv, va[j], acc[i][j]);
                        acc[i][4 + j] = fmaf(pv, vb[j], acc[i][4 + j]);
                    }
                }
            }
        }
        __syncthreads();   // PV done; safe to overwrite KVs next iter
    }

    // finalize: O / l, write out
    float* obase = o + ((size_t)(b * CN + q0)) * CHS + h * CDK;
#pragma unroll
    for (int i = 0; i < 4; ++i) {
        float inv = 1.0f / l_s[ty * 4 + i];
        float4 o0, o1;
        float* p0 = &o0.x;
        float* p1 = &o1.x;
#pragma unroll
        for (int j = 0; j < 4; ++j) {
            p0[j] = acc[i][j] * inv;
            p1[j] = acc[i][4 + j] * inv;
        }
        *reinterpret_cast<float4*>(obase + (size_t)(ty * 4 + i) * CHS + tx * 8) = o0;
        *reinterpret_cast<float4*>(obase + (size_t)(ty * 4 + i) * CHS + tx * 8 + 4) = o1;
    }
}

// ---------------------------------------------------------------------------
// LayerNorm (row=512), optional residual add. One wave (64 lanes) per row.
// out may alias x or res: each thread reads its 8 elems before writing them.
// ---------------------------------------------------------------------------
__global__ __launch_bounds__(256) void ln_kernel(
    const float* __restrict__ x, const float* __restrict__ res,
    const float* __restrict__ g, const float* __restrict__ beta,
    float* __restrict__ out)
{
    const int lane = threadIdx.x & 63;
    const int row = blockIdx.x * 4 + (threadIdx.x >> 6);
    const float* xr = x + (size_t)row * CHS + lane * 8;

    float4 v0 = *reinterpret_cast<const float4*>(xr);
    float4 v1 = *reinterpret_cast<const float4*>(xr + 4);
    if (res) {
        const float* rr = res + (size_t)row * CHS + lane * 8;
        float4 r0 = *reinterpret_cast<const float4*>(rr);
        float4 r1 = *reinterpret_cast<const float4*>(rr + 4);
        v0.x += r0.x; v0.y += r0.y; v0.z += r0.z; v0.w += r0.w;
        v1.x += r1.x; v1.y += r1.y; v1.z += r1.z; v1.w += r1.w;
    }
    float vals[8] = {v0.x, v0.y, v0.z, v0.w, v1.x, v1.y, v1.z, v1.w};

    float sum = 0.f;
#pragma unroll
    for (int i = 0; i < 8; ++i) sum += vals[i];
#pragma unroll
    for (int off = 32; off > 0; off >>= 1) sum += __shfl_xor(sum, off);
    float mean = sum * (1.0f / 512.0f);

    float var = 0.f;
#pragma unroll
    for (int i = 0; i < 8; ++i) {
        float d = vals[i] - mean;
        var += d * d;
    }
#pragma unroll
    for (int off = 32; off > 0; off >>= 1) var += __shfl_xor(var, off);
    var *= (1.0f / 512.0f);
    float rs = rsqrtf(var + 1e-5f);

    float4 g0 = *reinterpret_cast<const float4*>(g + lane * 8);
    float4 g1 = *reinterpret_cast<const float4*>(g + lane * 8 + 4);
    float4 b0 = *reinterpret_cast<const float4*>(beta + lane * 8);
    float4 b1 = *reinterpret_cast<const float4*>(beta + lane * 8 + 4);
    const float* gp0 = &g0.x; const float* gp1 = &g1.x;
    const float* bp0 = &b0.x; const float* bp1 = &b1.x;

    float4 o0, o1;
    float* q0 = &o0.x; float* q1 = &o1.x;
#pragma unroll
    for (int i = 0; i < 4; ++i) {
        q0[i] = (vals[i] - mean) * rs * gp0[i] + bp0[i];
        q1[i] = (vals[4 + i] - mean) * rs * gp1[i] + bp1[i];
    }
    float* orow = out + (size_t)row * CHS + lane * 8;
    *reinterpret_cast<float4*>(orow) = o0;
    *reinterpret_cast<float4*>(orow + 4) = o1;
}

// ---------------------------------------------------------------------------
// Outputs: glob (B,512) then gents (B,N,512), concatenated flat.
// ---------------------------------------------------------------------------
__global__ __launch_bounds__(256) void write_out_kernel(
    const float* __restrict__ vg, float* __restrict__ out)
{
    int i = blockIdx.x * 256 + threadIdx.x;       // float4 index over gents
    float4 v = reinterpret_cast<const float4*>(vg)[i];
    reinterpret_cast<float4*>(out + 2048)[i] = v;
    if (i < 512) {                                 // glob: 2048 floats
        int b = i >> 7;
        int c4 = i & 127;
        reinterpret_cast<float4*>(out)[i] =
            reinterpret_cast<const float4*>(vg)[((size_t)(b * CN + CE) * CHS) / 4 + c4];
    }
}

// ---------------------------------------------------------------------------
// Workspace layout (6 x 16 MB = 96 MB):
//   s0: vg, later t (vg is dead after the QKV GEMMs)
//   s1..s4: q,k,v,o; later the contiguous 64 MB h buffer (all dead by then)
//   s5: f
// ---------------------------------------------------------------------------
extern "C" void kernel_launch(void* const* d_in, const int* in_sizes, int n_in,
                              void* d_out, int out_size, void* d_ws, size_t ws_size,
                              hipStream_t stream)
{
    (void)in_sizes; (void)n_in; (void)out_size; (void)ws_size;

    const int*   adj    = (const int*)d_in[0];
    const int*   rels   = (const int*)d_in[1];
    const float* vents  = (const float*)d_in[2];
    const float* renc_w = (const float*)d_in[3];
    const float* Wq     = (const float*)d_in[4];
    const float* bq     = (const float*)d_in[5];
    const float* Wk     = (const float*)d_in[6];
    const float* bk     = (const float*)d_in[7];
    const float* Wv     = (const float*)d_in[8];
    const float* bv     = (const float*)d_in[9];
    const float* Wo     = (const float*)d_in[10];
    const float* bo     = (const float*)d_in[11];
    const float* l1w    = (const float*)d_in[12];
    const float* l1b    = (const float*)d_in[13];
    const float* l2w    = (const float*)d_in[14];
    const float* l2b    = (const float*)d_in[15];
    const float* prelu  = (const float*)d_in[16];
    const float* lng    = (const float*)d_in[17];
    const float* lnb    = (const float*)d_in[18];

    float* ws = (float*)d_ws;
    const size_t M4 = (size_t)CM * CHS;   // 4,194,304 floats (16 MB)
    float* s0 = ws;                        // vg / t
    float* s1 = ws + 1 * M4;               // q / h[0]
    float* s2 = ws + 2 * M4;               // k / h[1]
    float* s3 = ws + 3 * M4;               // v / h[2]
    float* s4 = ws + 4 * M4;               // o / h[3]
    float* s5 = ws + 5 * M4;               // f

    build_vg_kernel<<<4096, 256, 0, stream>>>(vents, renc_w, rels, s0);

    for (int j = 0; j < 2; ++j) {
        const float* Wq_j = Wq + (size_t)j * CHS * CHS;
        const float* Wk_j = Wk + (size_t)j * CHS * CHS;
        const float* Wv_j = Wv + (size_t)j * CHS * CHS;
        const float* Wo_j = Wo + (size_t)j * CHS * CHS;
        const float* bq_j = bq + j * CHS;
        const float* bk_j = bk + j * CHS;
        const float* bv_j = bv + j * CHS;
        const float* bo_j = bo + j * CHS;
        const float* l1w_j = l1w + (size_t)j * CHS * 4 * CHS;
        const float* l1b_j = l1b + j * 4 * CHS;
        const float* l2w_j = l2w + (size_t)j * 4 * CHS * CHS;
        const float* l2b_j = l2b + j * CHS;
        const float* pr_j  = prelu + j * 4 * CHS;
        const float* g_j   = lng + j * CHS;
        const float* b_j   = lnb + j * CHS;

        dim3 g512(CHS / GBN, CM / GBM);            // (8, 64)
        gemm_bias_kernel<<<g512, 256, 0, stream>>>(s0, Wq_j, bq_j, nullptr, s1, CHS, CHS);
        gemm_bias_kernel<<<g512, 256, 0, stream>>>(s0, Wk_j, bk_j, nullptr, s2, CHS, CHS);
        gemm_bias_kernel<<<g512, 256, 0, stream>>>(s0, Wv_j, bv_j, nullptr, s3, CHS, CHS);

        attn_kernel<<<dim3(CN / ABQ, CNH, CB), 512, 0, stream>>>(s1, s2, s3, adj, s4);

        // o @ Wo + bo -> s1 ; t = LN(s1) -> s0 (vg dead from here on)
        gemm_bias_kernel<<<g512, 256, 0, stream>>>(s4, Wo_j, bo_j, nullptr, s1, CHS, CHS);
        ln_kernel<<<CM / 4, 256, 0, stream>>>(s1, nullptr, g_j, b_j, s0);

        // h = prelu(t @ l1w + l1b) -> s1..s4 (contiguous 64 MB)
        gemm_bias_kernel<<<dim3(4 * CHS / GBN, CM / GBM), 256, 0, stream>>>(
            s0, l1w_j, l1b_j, pr_j, s1, CHS, 4 * CHS);
        // f = h @ l2w + l2b -> s5
        gemm_bias_kernel<<<g512, 256, 0, stream>>>(s1, l2w_j, l2b_j, nullptr, s5, 4 * CHS, CHS);

        // vg = LN(f + t) -> s0
        ln_kernel<<<CM / 4, 256, 0, stream>>>(s5, s0, g_j, b_j, s0);
    }

    write_out_kernel<<<4096, 256, 0, stream>>>(s0, (float*)d_out);
}

// Round 8
// 2659.877 us; speedup vs baseline: 5.9105x; 5.9105x over previous
//
#include <hip/hip_runtime.h>
#include <math.h>

// Problem constants (from reference)
constexpr int CB = 4;
constexpr int CE = 1536;
constexpr int CR = 512;
constexpr int CN = 2048;          // E + R
constexpr int CHS = 512;          // HSZ
constexpr int CNH = 4;            // heads
constexpr int CDK = 128;          // head dim
constexpr int CM = CB * CN;       // 8192 rows
constexpr float CNEG = -1000000000.0f;

// ---------------------------------------------------------------------------
// vg = concat(vents, renc_w[rels]) : (B, N, 512)
// ---------------------------------------------------------------------------
__global__ __launch_bounds__(256) void build_vg_kernel(
    const float* __restrict__ vents, const float* __restrict__ renc,
    const int* __restrict__ rels, float* __restrict__ vg)
{
    int i = blockIdx.x * 256 + threadIdx.x;      // float4 index, 1,048,576 total
    int row = i >> 7;                            // / (512/4)
    int c4 = i & 127;
    int b = row / CN;
    int n = row % CN;
    const float4* src;
    if (n < CE) {
        src = reinterpret_cast<const float4*>(vents + ((size_t)b * CE + n) * CHS);
    } else {
        int r = rels[b * CR + (n - CE)];
        src = reinterpret_cast<const float4*>(renc + (size_t)r * CHS);
    }
    reinterpret_cast<float4*>(vg)[(size_t)row * 128 + c4] = src[c4];
}

// ---------------------------------------------------------------------------
// C = A(M,K) @ W(K,Nc) + bias [+ PReLU(col)]  — fp32 tiled, 128x64 tile
// ---------------------------------------------------------------------------
#define GBM 128
#define GBN 64
#define GBK 16

__global__ __launch_bounds__(256) void gemm_bias_kernel(
    const float* __restrict__ A, const float* __restrict__ W,
    const float* __restrict__ bias, const float* __restrict__ prelu,
    float* __restrict__ C, int K, int Nc)
{
    __shared__ float As[GBK][GBM + 4];
    __shared__ float Bs[GBK][GBN + 4];
    const int tid = threadIdx.x;
    const int bm = blockIdx.y * GBM;
    const int bn = blockIdx.x * GBN;
    const int tx = tid & 15;
    const int ty = tid >> 4;

    float acc[8][4];
#pragma unroll
    for (int i = 0; i < 8; ++i)
#pragma unroll
        for (int j = 0; j < 4; ++j) acc[i][j] = 0.f;

    for (int k0 = 0; k0 < K; k0 += GBK) {
        // A tile 128x16 (stored transposed), 2 float4 per thread
#pragma unroll
        for (int l = 0; l < 2; ++l) {
            int idx = tid + l * 256;
            int r = idx >> 2;
            int c = (idx & 3) << 2;
            float4 av = *reinterpret_cast<const float4*>(A + (size_t)(bm + r) * K + k0 + c);
            As[c + 0][r] = av.x; As[c + 1][r] = av.y;
            As[c + 2][r] = av.z; As[c + 3][r] = av.w;
        }
        // B tile 16x64, 1 float4 per thread
        {
            int r = tid >> 4;
            int c = (tid & 15) << 2;
            float4 bv = *reinterpret_cast<const float4*>(W + (size_t)(k0 + r) * Nc + bn + c);
            Bs[r][c + 0] = bv.x; Bs[r][c + 1] = bv.y;
            Bs[r][c + 2] = bv.z; Bs[r][c + 3] = bv.w;
        }
        __syncthreads();
#pragma unroll
        for (int kk = 0; kk < GBK; ++kk) {
            float a[8], b[4];
#pragma unroll
            for (int i = 0; i < 8; ++i) a[i] = As[kk][ty * 8 + i];
#pragma unroll
            for (int j = 0; j < 4; ++j) b[j] = Bs[kk][tx * 4 + j];
#pragma unroll
            for (int i = 0; i < 8; ++i)
#pragma unroll
                for (int j = 0; j < 4; ++j)
                    acc[i][j] = fmaf(a[i], b[j], acc[i][j]);
        }
        __syncthreads();
    }

    float bv[4], al[4];
#pragma unroll
    for (int j = 0; j < 4; ++j) bv[j] = bias[bn + tx * 4 + j];
    if (prelu) {
#pragma unroll
        for (int j = 0; j < 4; ++j) al[j] = prelu[bn + tx * 4 + j];
    }
#pragma unroll
    for (int i = 0; i < 8; ++i) {
        float4 o;
        float* po = &o.x;
#pragma unroll
        for (int j = 0; j < 4; ++j) {
            float vv = acc[i][j] + bv[j];
            if (prelu) vv = vv > 0.f ? vv : al[j] * vv;   // max(v,0)+a*min(v,0)
            po[j] = vv;
        }
        *reinterpret_cast<float4*>(C + (size_t)(bm + ty * 8 + i) * Nc + bn + tx * 4) = o;
    }
}

// ---------------------------------------------------------------------------
// Flash attention with adjacency mask. One wg per (b, h, 128-row Q block).
// 512 threads. S micro 4x4 (ty=tid>>4 in 0..31, tx=tid&15), O micro 4x8.
// LDS ≈ 134.5 KB -> 1 wg/CU = 8 waves = 2 waves/SIMD.
//
// R5 post-mortem: __launch_bounds__(512,2) left VGPR_Count at 128 — exactly
// the budget for 4 waves/SIMD (pool: 512 regs/slot, m69), i.e. the 2nd arg
// was taken as min BLOCKS/CU (CUDA semantics). (512,1) -> 8 waves/CU ->
// 256-VGPR budget (>=256 under either semantics). Also: the full
// `#pragma unroll` on the kk (32 iters x 8 float4 LDS loads) and m (16
// iters x 12 float4) loops invited massive load hoisting -> register
// demand >> budget -> 23 GB scratch per dispatch. Bounded to unroll 2.
// KVS_LD reverted to CDK+4 (133 broke float4 16B alignment; conflicts
// went UP 1.34e8->2.22e8).
// ---------------------------------------------------------------------------
#define ABQ 128
#define ACH 64
#define KVS_LD (CDK + 4)   // 132 — keeps float4 LDS reads 16B-aligned

__global__ __launch_bounds__(512, 1) void attn_kernel(
    const float* __restrict__ q, const float* __restrict__ k,
    const float* __restrict__ v, const int* __restrict__ adj,
    float* __restrict__ o)
{
    __shared__ float Qs[ABQ][CDK + 4];   // 67.6 KB
    __shared__ float KVs[ACH][KVS_LD];   // 33.8 KB (K then V)
    __shared__ float Ps[ABQ][ACH + 4];   // 34.8 KB
    __shared__ float m_s[ABQ], l_s[ABQ], a_s[ABQ];

    const int tid = threadIdx.x;
    const int b = blockIdx.z, h = blockIdx.y;
    const int q0 = blockIdx.x * ABQ;
    const int tx = tid & 15;
    const int ty = tid >> 4;             // 0..31
    const float scale = 0.08838834764831845f;   // 1/sqrt(128)

    // load Q tile (128 x 128)
    const float* qbase = q + ((size_t)(b * CN + q0)) * CHS + h * CDK;
#pragma unroll
    for (int l = 0; l < 8; ++l) {
        int idx = tid + l * 512;
        int r = idx >> 5;
        int c = (idx & 31) << 2;
        *reinterpret_cast<float4*>(&Qs[r][c]) =
            *reinterpret_cast<const float4*>(qbase + (size_t)r * CHS + c);
    }
    if (tid < ABQ) { m_s[tid] = -INFINITY; l_s[tid] = 0.f; }

    float acc[4][8];
#pragma unroll
    for (int i = 0; i < 4; ++i)
#pragma unroll
        for (int j = 0; j < 8; ++j) acc[i][j] = 0.f;
    __syncthreads();

    for (int k0 = 0; k0 < CN; k0 += ACH) {
        // load K chunk (64 x 128)
        const float* kbase = k + ((size_t)(b * CN + k0)) * CHS + h * CDK;
#pragma unroll
        for (int l = 0; l < 4; ++l) {
            int idx = tid + l * 512;
            int r = idx >> 5;
            int c = (idx & 31) << 2;
            *reinterpret_cast<float4*>(&KVs[r][c]) =
                *reinterpret_cast<const float4*>(kbase + (size_t)r * CHS + c);
        }
        __syncthreads();

        // S = Q K^T (4x4 per thread) — unroll bounded (see header comment)
        float s[4][4];
#pragma unroll
        for (int i = 0; i < 4; ++i)
#pragma unroll
            for (int j = 0; j < 4; ++j) s[i][j] = 0.f;
#pragma unroll 2
        for (int kk = 0; kk < CDK; kk += 4) {
            float4 a4[4], b4[4];
#pragma unroll
            for (int i = 0; i < 4; ++i)
                a4[i] = *reinterpret_cast<const float4*>(&Qs[ty * 4 + i][kk]);
#pragma unroll
            for (int j = 0; j < 4; ++j)
                b4[j] = *reinterpret_cast<const float4*>(&KVs[tx * 4 + j][kk]);
#pragma unroll
            for (int i = 0; i < 4; ++i)
#pragma unroll
                for (int j = 0; j < 4; ++j) {
                    s[i][j] = fmaf(a4[i].x, b4[j].x, s[i][j]);
                    s[i][j] = fmaf(a4[i].y, b4[j].y, s[i][j]);
                    s[i][j] = fmaf(a4[i].z, b4[j].z, s[i][j]);
                    s[i][j] = fmaf(a4[i].w, b4[j].w, s[i][j]);
                }
        }

        // mask + scale  (reference: scale first, then mask — equivalent here)
#pragma unroll
        for (int i = 0; i < 4; ++i) {
            int4 av = *reinterpret_cast<const int4*>(
                adj + ((size_t)b * CN + q0 + ty * 4 + i) * CN + k0 + tx * 4);
            const int* ap = &av.x;
#pragma unroll
            for (int j = 0; j < 4; ++j)
                s[i][j] = (ap[j] == 0) ? CNEG : s[i][j] * scale;
        }

        // per-row chunk max over 64 cols (16 lanes x 4 each)
        float rmax[4];
#pragma unroll
        for (int i = 0; i < 4; ++i)
            rmax[i] = fmaxf(fmaxf(s[i][0], s[i][1]), fmaxf(s[i][2], s[i][3]));
#pragma unroll
        for (int off = 1; off < 16; off <<= 1)
#pragma unroll
            for (int i = 0; i < 4; ++i)
                rmax[i] = fmaxf(rmax[i], __shfl_xor(rmax[i], off, 16));

        // NOTE: rows are owned by a 16-lane group entirely inside one wave,
        // so the read-modify-write of m_s/l_s below is wave-lockstep-safe.
        float mold[4], mnew[4], alpha[4], rsum[4];
#pragma unroll
        for (int i = 0; i < 4; ++i) {
            mold[i] = m_s[ty * 4 + i];
            mnew[i] = fmaxf(mold[i], rmax[i]);
            alpha[i] = __expf(mold[i] - mnew[i]);
            rsum[i] = 0.f;
        }
        // P = exp(S - mnew), write to LDS, accumulate row sums
#pragma unroll
        for (int i = 0; i < 4; ++i) {
            float4 p4;
            float* pp = &p4.x;
#pragma unroll
            for (int j = 0; j < 4; ++j) {
                float p = __expf(s[i][j] - mnew[i]);
                pp[j] = p;
                rsum[i] += p;
            }
            *reinterpret_cast<float4*>(&Ps[ty * 4 + i][tx * 4]) = p4;
        }
#pragma unroll
        for (int off = 1; off < 16; off <<= 1)
#pragma unroll
            for (int i = 0; i < 4; ++i)
                rsum[i] += __shfl_xor(rsum[i], off, 16);
        if (tx == 0) {
#pragma unroll
            for (int i = 0; i < 4; ++i) {
                int r = ty * 4 + i;
                l_s[r] = l_s[r] * alpha[i] + rsum[i];
                m_s[r] = mnew[i];
                a_s[r] = alpha[i];
            }
        }
        __syncthreads();   // S/P done; safe to overwrite KVs, Ps visible

        // load V chunk (64 x 128) into KVs
        const float* vbase = v + ((size_t)(b * CN + k0)) * CHS + h * CDK;
#pragma unroll
        for (int l = 0; l < 4; ++l) {
            int idx = tid + l * 512;
            int r = idx >> 5;
            int c = (idx & 31) << 2;
            *reinterpret_cast<float4*>(&KVs[r][c]) =
                *reinterpret_cast<const float4*>(vbase + (size_t)r * CHS + c);
        }
        __syncthreads();

        // O = O*alpha + P @ V   (rows ty*4.., cols tx*8..)
        float alv[4];
#pragma unroll
        for (int i = 0; i < 4; ++i) alv[i] = a_s[ty * 4 + i];
#pragma unroll
        for (int i = 0; i < 4; ++i)
#pragma unroll
            for (int j = 0; j < 8; ++j) acc[i][j] *= alv[i];

#pragma unroll 2
        for (int m = 0; m < ACH; m += 4) {
            float4 p4[4];
#pragma unroll
            for (int i = 0; i < 4; ++i)
                p4[i] = *reinterpret_cast<const float4*>(&Ps[ty * 4 + i][m]);
            float4 v0[4], v1[4];
#pragma unroll
            for (int mm = 0; mm < 4; ++mm) {
                v0[mm] = *reinterpret_cast<const float4*>(&KVs[m + mm][tx * 8]);
                v1[mm] = *reinterpret_cast<const float4*>(&KVs[m + mm][tx * 8 + 4]);
            }
#pragma unroll
            for (int i = 0; i < 4; ++i) {
                const float* pp = &p4[i].x;
#pragma unroll
                for (int mm = 0; mm < 4; ++mm) {
                    float pv = pp[mm];
                    const float* va = &v0[mm].x;
                    const float* vb = &v1[mm].x;
#pragma unroll
                    for (int j = 0; j < 4; ++j) {
                        acc[i][j]     = fmaf(pv, va[j], acc[i][j]);
                        acc[i][4 + j] = fmaf(pv, vb[j], acc[i][4 + j]);
                    }
                }
            }
        }
        __syncthreads();   // PV done; safe to overwrite KVs next iter
    }

    // finalize: O / l, write out
    float* obase = o + ((size_t)(b * CN + q0)) * CHS + h * CDK;
#pragma unroll
    for (int i = 0; i < 4; ++i) {
        float inv = 1.0f / l_s[ty * 4 + i];
        float4 o0, o1;
        float* p0 = &o0.x;
        float* p1 = &o1.x;
#pragma unroll
        for (int j = 0; j < 4; ++j) {
            p0[j] = acc[i][j] * inv;
            p1[j] = acc[i][4 + j] * inv;
        }
        *reinterpret_cast<float4*>(obase + (size_t)(ty * 4 + i) * CHS + tx * 8) = o0;
        *reinterpret_cast<float4*>(obase + (size_t)(ty * 4 + i) * CHS + tx * 8 + 4) = o1;
    }
}

// ---------------------------------------------------------------------------
// LayerNorm (row=512), optional residual add. One wave (64 lanes) per row.
// out may alias x or res: each thread reads its 8 elems before writing them.
// ---------------------------------------------------------------------------
__global__ __launch_bounds__(256) void ln_kernel(
    const float* __restrict__ x, const float* __restrict__ res,
    const float* __restrict__ g, const float* __restrict__ beta,
    float* __restrict__ out)
{
    const int lane = threadIdx.x & 63;
    const int row = blockIdx.x * 4 + (threadIdx.x >> 6);
    const float* xr = x + (size_t)row * CHS + lane * 8;

    float4 v0 = *reinterpret_cast<const float4*>(xr);
    float4 v1 = *reinterpret_cast<const float4*>(xr + 4);
    if (res) {
        const float* rr = res + (size_t)row * CHS + lane * 8;
        float4 r0 = *reinterpret_cast<const float4*>(rr);
        float4 r1 = *reinterpret_cast<const float4*>(rr + 4);
        v0.x += r0.x; v0.y += r0.y; v0.z += r0.z; v0.w += r0.w;
        v1.x += r1.x; v1.y += r1.y; v1.z += r1.z; v1.w += r1.w;
    }
    float vals[8] = {v0.x, v0.y, v0.z, v0.w, v1.x, v1.y, v1.z, v1.w};

    float sum = 0.f;
#pragma unroll
    for (int i = 0; i < 8; ++i) sum += vals[i];
#pragma unroll
    for (int off = 32; off > 0; off >>= 1) sum += __shfl_xor(sum, off);
    float mean = sum * (1.0f / 512.0f);

    float var = 0.f;
#pragma unroll
    for (int i = 0; i < 8; ++i) {
        float d = vals[i] - mean;
        var += d * d;
    }
#pragma unroll
    for (int off = 32; off > 0; off >>= 1) var += __shfl_xor(var, off);
    var *= (1.0f / 512.0f);
    float rs = rsqrtf(var + 1e-5f);

    float4 g0 = *reinterpret_cast<const float4*>(g + lane * 8);
    float4 g1 = *reinterpret_cast<const float4*>(g + lane * 8 + 4);
    float4 b0 = *reinterpret_cast<const float4*>(beta + lane * 8);
    float4 b1 = *reinterpret_cast<const float4*>(beta + lane * 8 + 4);
    const float* gp0 = &g0.x; const float* gp1 = &g1.x;
    const float* bp0 = &b0.x; const float* bp1 = &b1.x;

    float4 o0, o1;
    float* q0 = &o0.x; float* q1 = &o1.x;
#pragma unroll
    for (int i = 0; i < 4; ++i) {
        q0[i] = (vals[i] - mean) * rs * gp0[i] + bp0[i];
        q1[i] = (vals[4 + i] - mean) * rs * gp1[i] + bp1[i];
    }
    float* orow = out + (size_t)row * CHS + lane * 8;
    *reinterpret_cast<float4*>(orow) = o0;
    *reinterpret_cast<float4*>(orow + 4) = o1;
}

// ---------------------------------------------------------------------------
// Outputs: glob (B,512) then gents (B,N,512), concatenated flat.
// ---------------------------------------------------------------------------
__global__ __launch_bounds__(256) void write_out_kernel(
    const float* __restrict__ vg, float* __restrict__ out)
{
    int i = blockIdx.x * 256 + threadIdx.x;       // float4 index over gents
    float4 v = reinterpret_cast<const float4*>(vg)[i];
    reinterpret_cast<float4*>(out + 2048)[i] = v;
    if (i < 512) {                                 // glob: 2048 floats
        int b = i >> 7;
        int c4 = i & 127;
        reinterpret_cast<float4*>(out)[i] =
            reinterpret_cast<const float4*>(vg)[((size_t)(b * CN + CE) * CHS) / 4 + c4];
    }
}

// ---------------------------------------------------------------------------
// Workspace layout (6 x 16 MB = 96 MB):
//   s0: vg, later t (vg is dead after the QKV GEMMs)
//   s1..s4: q,k,v,o; later the contiguous 64 MB h buffer (all dead by then)
//   s5: f
// ---------------------------------------------------------------------------
extern "C" void kernel_launch(void* const* d_in, const int* in_sizes, int n_in,
                              void* d_out, int out_size, void* d_ws, size_t ws_size,
                              hipStream_t stream)
{
    (void)in_sizes; (void)n_in; (void)out_size; (void)ws_size;

    const int*   adj    = (const int*)d_in[0];
    const int*   rels   = (const int*)d_in[1];
    const float* vents  = (const float*)d_in[2];
    const float* renc_w = (const float*)d_in[3];
    const float* Wq     = (const float*)d_in[4];
    const float* bq     = (const float*)d_in[5];
    const float* Wk     = (const float*)d_in[6];
    const float* bk     = (const float*)d_in[7];
    const float* Wv     = (const float*)d_in[8];
    const float* bv     = (const float*)d_in[9];
    const float* Wo     = (const float*)d_in[10];
    const float* bo     = (const float*)d_in[11];
    const float* l1w    = (const float*)d_in[12];
    const float* l1b    = (const float*)d_in[13];
    const float* l2w    = (const float*)d_in[14];
    const float* l2b    = (const float*)d_in[15];
    const float* prelu  = (const float*)d_in[16];
    const float* lng    = (const float*)d_in[17];
    const float* lnb    = (const float*)d_in[18];

    float* ws = (float*)d_ws;
    const size_t M4 = (size_t)CM * CHS;   // 4,194,304 floats (16 MB)
    float* s0 = ws;                        // vg / t
    float* s1 = ws + 1 * M4;               // q / h[0]
    float* s2 = ws + 2 * M4;               // k / h[1]
    float* s3 = ws + 3 * M4;               // v / h[2]
    float* s4 = ws + 4 * M4;               // o / h[3]
    float* s5 = ws + 5 * M4;               // f

    build_vg_kernel<<<4096, 256, 0, stream>>>(vents, renc_w, rels, s0);

    for (int j = 0; j < 2; ++j) {
        const float* Wq_j = Wq + (size_t)j * CHS * CHS;
        const float* Wk_j = Wk + (size_t)j * CHS * CHS;
        const float* Wv_j = Wv + (size_t)j * CHS * CHS;
        const float* Wo_j = Wo + (size_t)j * CHS * CHS;
        const float* bq_j = bq + j * CHS;
        const float* bk_j = bk + j * CHS;
        const float* bv_j = bv + j * CHS;
        const float* bo_j = bo + j * CHS;
        const float* l1w_j = l1w + (size_t)j * CHS * 4 * CHS;
        const float* l1b_j = l1b + j * 4 * CHS;
        const float* l2w_j = l2w + (size_t)j * 4 * CHS * CHS;
        const float* l2b_j = l2b + j * CHS;
        const float* pr_j  = prelu + j * 4 * CHS;
        const float* g_j   = lng + j * CHS;
        const float* b_j   = lnb + j * CHS;

        dim3 g512(CHS / GBN, CM / GBM);            // (8, 64)
        gemm_bias_kernel<<<g512, 256, 0, stream>>>(s0, Wq_j, bq_j, nullptr, s1, CHS, CHS);
        gemm_bias_kernel<<<g512, 256, 0, stream>>>(s0, Wk_j, bk_j, nullptr, s2, CHS, CHS);
        gemm_bias_kernel<<<g512, 256, 0, stream>>>(s0, Wv_j, bv_j, nullptr, s3, CHS, CHS);

        attn_kernel<<<dim3(CN / ABQ, CNH, CB), 512, 0, stream>>>(s1, s2, s3, adj, s4);

        // o @ Wo + bo -> s1 ; t = LN(s1) -> s0 (vg dead from here on)
        gemm_bias_kernel<<<g512, 256, 0, stream>>>(s4, Wo_j, bo_j, nullptr, s1, CHS, CHS);
        ln_kernel<<<CM / 4, 256, 0, stream>>>(s1, nullptr, g_j, b_j, s0);

        // h = prelu(t @ l1w + l1b) -> s1..s4 (contiguous 64 MB)
        gemm_bias_kernel<<<dim3(4 * CHS / GBN, CM / GBM), 256, 0, stream>>>(
            s0, l1w_j, l1b_j, pr_j, s1, CHS, 4 * CHS);
        // f = h @ l2w + l2b -> s5
        gemm_bias_kernel<<<g512, 256, 0, stream>>>(s1, l2w_j, l2b_j, nullptr, s5, 4 * CHS, CHS);

        // vg = LN(f + t) -> s0
        ln_kernel<<<CM / 4, 256, 0, stream>>>(s5, s0, g_j, b_j, s0);
    }

    write_out_kernel<<<4096, 256, 0, stream>>>(s0, (float*)d_out);
}

// Round 11
// 2581.918 us; speedup vs baseline: 6.0890x; 1.0302x over previous
//
#include <hip/hip_runtime.h>
#include <math.h>

// Problem constants (from reference)
constexpr int CB = 4;
constexpr int CE = 1536;
constexpr int CR = 512;
constexpr int CN = 2048;          // E + R
constexpr int CHS = 512;          // HSZ
constexpr int CNH = 4;            // heads
constexpr int CDK = 128;          // head dim
constexpr int CM = CB * CN;       // 8192 rows
constexpr float CNEG = -1000000000.0f;

// ---------------------------------------------------------------------------
// vg = concat(vents, renc_w[rels]) : (B, N, 512)
// ---------------------------------------------------------------------------
__global__ __launch_bounds__(256) void build_vg_kernel(
    const float* __restrict__ vents, const float* __restrict__ renc,
    const int* __restrict__ rels, float* __restrict__ vg)
{
    int i = blockIdx.x * 256 + threadIdx.x;      // float4 index, 1,048,576 total
    int row = i >> 7;                            // / (512/4)
    int c4 = i & 127;
    int b = row / CN;
    int n = row % CN;
    const float4* src;
    if (n < CE) {
        src = reinterpret_cast<const float4*>(vents + ((size_t)b * CE + n) * CHS);
    } else {
        int r = rels[b * CR + (n - CE)];
        src = reinterpret_cast<const float4*>(renc + (size_t)r * CHS);
    }
    reinterpret_cast<float4*>(vg)[(size_t)row * 128 + c4] = src[c4];
}

// ---------------------------------------------------------------------------
// C = A(M,K) @ W(K,Nc) + bias [+ PReLU(col)]  — fp32 tiled, 128x64 tile
// ---------------------------------------------------------------------------
#define GBM 128
#define GBN 64
#define GBK 16

__global__ __launch_bounds__(256) void gemm_bias_kernel(
    const float* __restrict__ A, const float* __restrict__ W,
    const float* __restrict__ bias, const float* __restrict__ prelu,
    float* __restrict__ C, int K, int Nc)
{
    __shared__ float As[GBK][GBM + 4];
    __shared__ float Bs[GBK][GBN + 4];
    const int tid = threadIdx.x;
    const int bm = blockIdx.y * GBM;
    const int bn = blockIdx.x * GBN;
    const int tx = tid & 15;
    const int ty = tid >> 4;

    float acc[8][4];
#pragma unroll
    for (int i = 0; i < 8; ++i)
#pragma unroll
        for (int j = 0; j < 4; ++j) acc[i][j] = 0.f;

    for (int k0 = 0; k0 < K; k0 += GBK) {
        // A tile 128x16 (stored transposed), 2 float4 per thread
#pragma unroll
        for (int l = 0; l < 2; ++l) {
            int idx = tid + l * 256;
            int r = idx >> 2;
            int c = (idx & 3) << 2;
            float4 av = *reinterpret_cast<const float4*>(A + (size_t)(bm + r) * K + k0 + c);
            As[c + 0][r] = av.x; As[c + 1][r] = av.y;
            As[c + 2][r] = av.z; As[c + 3][r] = av.w;
        }
        // B tile 16x64, 1 float4 per thread
        {
            int r = tid >> 4;
            int c = (tid & 15) << 2;
            float4 bv = *reinterpret_cast<const float4*>(W + (size_t)(k0 + r) * Nc + bn + c);
            Bs[r][c + 0] = bv.x; Bs[r][c + 1] = bv.y;
            Bs[r][c + 2] = bv.z; Bs[r][c + 3] = bv.w;
        }
        __syncthreads();
#pragma unroll
        for (int kk = 0; kk < GBK; ++kk) {
            float a[8], b[4];
#pragma unroll
            for (int i = 0; i < 8; ++i) a[i] = As[kk][ty * 8 + i];
#pragma unroll
            for (int j = 0; j < 4; ++j) b[j] = Bs[kk][tx * 4 + j];
#pragma unroll
            for (int i = 0; i < 8; ++i)
#pragma unroll
                for (int j = 0; j < 4; ++j)
                    acc[i][j] = fmaf(a[i], b[j], acc[i][j]);
        }
        __syncthreads();
    }

    float bv[4], al[4];
#pragma unroll
    for (int j = 0; j < 4; ++j) bv[j] = bias[bn + tx * 4 + j];
    if (prelu) {
#pragma unroll
        for (int j = 0; j < 4; ++j) al[j] = prelu[bn + tx * 4 + j];
    }
#pragma unroll
    for (int i = 0; i < 8; ++i) {
        float4 o;
        float* po = &o.x;
#pragma unroll
        for (int j = 0; j < 4; ++j) {
            float vv = acc[i][j] + bv[j];
            if (prelu) vv = vv > 0.f ? vv : al[j] * vv;   // max(v,0)+a*min(v,0)
            po[j] = vv;
        }
        *reinterpret_cast<float4*>(C + (size_t)(bm + ty * 8 + i) * Nc + bn + tx * 4) = o;
    }
}

// ---------------------------------------------------------------------------
// Flash attention with adjacency mask. One wg per (b, h, 128-row Q block).
// 512 threads. S micro 4x4 (ty=tid>>4 in 0..31, tx=tid&15).
// LDS ≈ 133 KB -> 1 wg/CU = 8 waves = 2 waves/SIMD.
//
// R8: spill fixed (WRITE 13.8GB->16MB, attn 7.1ms->670us) via bounded
// unrolls; VGPR=88. Remaining: SQ_LDS_BANK_CONFLICT 1.342e8 (~33%).
//
// R9 bank arithmetic (corrected): bank-quad of a float4 = block_idx mod 8.
// (a) R8's swizzle (XOR ((r>>2)&7)<<2) only perturbs block bits 2-4 —
//     mod 8 it contributes {0,4} only -> QK^T stays 8-way. BUG, never ran.
//     Correct: XOR the LOW 3 bits: blk' = blk ^ ((r>>2)&7).
//     QK^T rows 4tx+j -> masks tx&7 -> 8 quads, 2 rows each = 2-way (free).
// (b) PV V-read at c=tx*8 was ALWAYS 4-way (blocks 2tx mod 8 in {0,2,4,6},
//     4 lanes each) — row-uniform swizzle can't fix a within-row pattern.
//     Fix: each thread owns cols {tx*4..+3} and {tx*4+64..+67} instead of
//     {tx*8..+7}: v0 blocks {tx ^ M} cover all 8 quads twice = 2-way.
// Staging writes / Qs / Ps: permutation within row -> unchanged.
// ---------------------------------------------------------------------------
#define ABQ 128
#define ACH 64
// float offset of col c (multiple of 4) in swizzled row r of the KV tile
#define KVSWZ(r, c) ((r) * CDK + ((((c) >> 2) ^ (((r) >> 2) & 7)) << 2))

__global__ __launch_bounds__(512, 1) void attn_kernel(
    const float* __restrict__ q, const float* __restrict__ k,
    const float* __restrict__ v, const int* __restrict__ adj,
    float* __restrict__ o)
{
    __shared__ float Qs[ABQ][CDK + 4];   // 67.6 KB
    __shared__ float KVs[ACH * CDK];     // 32.0 KB, swizzled (K then V)
    __shared__ float Ps[ABQ][ACH + 4];   // 34.8 KB
    __shared__ float m_s[ABQ], l_s[ABQ], a_s[ABQ];

    const int tid = threadIdx.x;
    const int b = blockIdx.z, h = blockIdx.y;
    const int q0 = blockIdx.x * ABQ;
    const int tx = tid & 15;
    const int ty = tid >> 4;             // 0..31
    const float scale = 0.08838834764831845f;   // 1/sqrt(128)

    // load Q tile (128 x 128)
    const float* qbase = q + ((size_t)(b * CN + q0)) * CHS + h * CDK;
#pragma unroll
    for (int l = 0; l < 8; ++l) {
        int idx = tid + l * 512;
        int r = idx >> 5;
        int c = (idx & 31) << 2;
        *reinterpret_cast<float4*>(&Qs[r][c]) =
            *reinterpret_cast<const float4*>(qbase + (size_t)r * CHS + c);
    }
    if (tid < ABQ) { m_s[tid] = -INFINITY; l_s[tid] = 0.f; }

    // acc[i][0..3] = cols tx*4..+3 ; acc[i][4..7] = cols tx*4+64..+67
    float acc[4][8];
#pragma unroll
    for (int i = 0; i < 4; ++i)
#pragma unroll
        for (int j = 0; j < 8; ++j) acc[i][j] = 0.f;
    __syncthreads();

    for (int k0 = 0; k0 < CN; k0 += ACH) {
        // load K chunk (64 x 128) into swizzled KVs
        const float* kbase = k + ((size_t)(b * CN + k0)) * CHS + h * CDK;
#pragma unroll
        for (int l = 0; l < 4; ++l) {
            int idx = tid + l * 512;
            int r = idx >> 5;
            int c = (idx & 31) << 2;
            *reinterpret_cast<float4*>(&KVs[KVSWZ(r, c)]) =
                *reinterpret_cast<const float4*>(kbase + (size_t)r * CHS + c);
        }
        __syncthreads();

        // S = Q K^T (4x4 per thread) — unroll bounded (register pressure)
        float s[4][4];
#pragma unroll
        for (int i = 0; i < 4; ++i)
#pragma unroll
            for (int j = 0; j < 4; ++j) s[i][j] = 0.f;
#pragma unroll 2
        for (int kk = 0; kk < CDK; kk += 4) {
            float4 a4[4], b4[4];
#pragma unroll
            for (int i = 0; i < 4; ++i)
                a4[i] = *reinterpret_cast<const float4*>(&Qs[ty * 4 + i][kk]);
#pragma unroll
            for (int j = 0; j < 4; ++j)
                b4[j] = *reinterpret_cast<const float4*>(&KVs[KVSWZ(tx * 4 + j, kk)]);
#pragma unroll
            for (int i = 0; i < 4; ++i)
#pragma unroll
                for (int j = 0; j < 4; ++j) {
                    s[i][j] = fmaf(a4[i].x, b4[j].x, s[i][j]);
                    s[i][j] = fmaf(a4[i].y, b4[j].y, s[i][j]);
                    s[i][j] = fmaf(a4[i].z, b4[j].z, s[i][j]);
                    s[i][j] = fmaf(a4[i].w, b4[j].w, s[i][j]);
                }
        }

        // mask + scale  (reference: scale first, then mask — equivalent here)
#pragma unroll
        for (int i = 0; i < 4; ++i) {
            int4 av = *reinterpret_cast<const int4*>(
                adj + ((size_t)b * CN + q0 + ty * 4 + i) * CN + k0 + tx * 4);
            const int* ap = &av.x;
#pragma unroll
            for (int j = 0; j < 4; ++j)
                s[i][j] = (ap[j] == 0) ? CNEG : s[i][j] * scale;
        }

        // per-row chunk max over 64 cols (16 lanes x 4 each)
        float rmax[4];
#pragma unroll
        for (int i = 0; i < 4; ++i)
            rmax[i] = fmaxf(fmaxf(s[i][0], s[i][1]), fmaxf(s[i][2], s[i][3]));
#pragma unroll
        for (int off = 1; off < 16; off <<= 1)
#pragma unroll
            for (int i = 0; i < 4; ++i)
                rmax[i] = fmaxf(rmax[i], __shfl_xor(rmax[i], off, 16));

        // NOTE: rows are owned by a 16-lane group entirely inside one wave,
        // so the read-modify-write of m_s/l_s below is wave-lockstep-safe.
        float mold[4], mnew[4], alpha[4], rsum[4];
#pragma unroll
        for (int i = 0; i < 4; ++i) {
            mold[i] = m_s[ty * 4 + i];
            mnew[i] = fmaxf(mold[i], rmax[i]);
            alpha[i] = __expf(mold[i] - mnew[i]);
            rsum[i] = 0.f;
        }
        // P = exp(S - mnew), write to LDS, accumulate row sums
#pragma unroll
        for (int i = 0; i < 4; ++i) {
            float4 p4;
            float* pp = &p4.x;
#pragma unroll
            for (int j = 0; j < 4; ++j) {
                float p = __expf(s[i][j] - mnew[i]);
                pp[j] = p;
                rsum[i] += p;
            }
            *reinterpret_cast<float4*>(&Ps[ty * 4 + i][tx * 4]) = p4;
        }
#pragma unroll
        for (int off = 1; off < 16; off <<= 1)
#pragma unroll
            for (int i = 0; i < 4; ++i)
                rsum[i] += __shfl_xor(rsum[i], off, 16);
        if (tx == 0) {
#pragma unroll
            for (int i = 0; i < 4; ++i) {
                int r = ty * 4 + i;
                l_s[r] = l_s[r] * alpha[i] + rsum[i];
                m_s[r] = mnew[i];
                a_s[r] = alpha[i];
            }
        }
        __syncthreads();   // S/P done; safe to overwrite KVs, Ps visible

        // load V chunk (64 x 128) into swizzled KVs
        const float* vbase = v + ((size_t)(b * CN + k0)) * CHS + h * CDK;
#pragma unroll
        for (int l = 0; l < 4; ++l) {
            int idx = tid + l * 512;
            int r = idx >> 5;
            int c = (idx & 31) << 2;
            *reinterpret_cast<float4*>(&KVs[KVSWZ(r, c)]) =
                *reinterpret_cast<const float4*>(vbase + (size_t)r * CHS + c);
        }
        __syncthreads();

        // O = O*alpha + P @ V   (rows ty*4.., col slices tx*4 and tx*4+64)
        float alv[4];
#pragma unroll
        for (int i = 0; i < 4; ++i) alv[i] = a_s[ty * 4 + i];
#pragma unroll
        for (int i = 0; i < 4; ++i)
#pragma unroll
            for (int j = 0; j < 8; ++j) acc[i][j] *= alv[i];

#pragma unroll 2
        for (int m = 0; m < ACH; m += 4) {
            float4 p4[4];
#pragma unroll
            for (int i = 0; i < 4; ++i)
                p4[i] = *reinterpret_cast<const float4*>(&Ps[ty * 4 + i][m]);
            float4 v0[4], v1[4];
#pragma unroll
            for (int mm = 0; mm < 4; ++mm) {
                v0[mm] = *reinterpret_cast<const float4*>(&KVs[KVSWZ(m + mm, tx * 4)]);
                v1[mm] = *reinterpret_cast<const float4*>(&KVs[KVSWZ(m + mm, tx * 4 + 64)]);
            }
#pragma unroll
            for (int i = 0; i < 4; ++i) {
                const float* pp = &p4[i].x;
#pragma unroll
                for (int mm = 0; mm < 4; ++mm) {
                    float pv = pp[mm];
                    const float* va = &v0[mm].x;
                    const float* vb = &v1[mm].x;
#pragma unroll
                    for (int j = 0; j < 4; ++j) {
                        acc[i][j]     = fmaf(pv, va[j], acc[i][j]);
                        acc[i][4 + j] = fmaf(pv, vb[j], acc[i][4 + j]);
                    }
                }
            }
        }
        __syncthreads();   // PV done; safe to overwrite KVs next iter
    }

    // finalize: O / l, write out (col slices tx*4 and tx*4+64)
    float* obase = o + ((size_t)(b * CN + q0)) * CHS + h * CDK;
#pragma unroll
    for (int i = 0; i < 4; ++i) {
        float inv = 1.0f / l_s[ty * 4 + i];
        float4 o0, o1;
        float* p0 = &o0.x;
        float* p1 = &o1.x;
#pragma unroll
        for (int j = 0; j < 4; ++j) {
            p0[j] = acc[i][j] * inv;
            p1[j] = acc[i][4 + j] * inv;
        }
        *reinterpret_cast<float4*>(obase + (size_t)(ty * 4 + i) * CHS + tx * 4) = o0;
        *reinterpret_cast<float4*>(obase + (size_t)(ty * 4 + i) * CHS + tx * 4 + 64) = o1;
    }
}

// ---------------------------------------------------------------------------
// LayerNorm (row=512), optional residual add. One wave (64 lanes) per row.
// out may alias x or res: each thread reads its 8 elems before writing them.
// ---------------------------------------------------------------------------
__global__ __launch_bounds__(256) void ln_kernel(
    const float* __restrict__ x, const float* __restrict__ res,
    const float* __restrict__ g, const float* __restrict__ beta,
    float* __restrict__ out)
{
    const int lane = threadIdx.x & 63;
    const int row = blockIdx.x * 4 + (threadIdx.x >> 6);
    const float* xr = x + (size_t)row * CHS + lane * 8;

    float4 v0 = *reinterpret_cast<const float4*>(xr);
    float4 v1 = *reinterpret_cast<const float4*>(xr + 4);
    if (res) {
        const float* rr = res + (size_t)row * CHS + lane * 8;
        float4 r0 = *reinterpret_cast<const float4*>(rr);
        float4 r1 = *reinterpret_cast<const float4*>(rr + 4);
        v0.x += r0.x; v0.y += r0.y; v0.z += r0.z; v0.w += r0.w;
        v1.x += r1.x; v1.y += r1.y; v1.z += r1.z; v1.w += r1.w;
    }
    float vals[8] = {v0.x, v0.y, v0.z, v0.w, v1.x, v1.y, v1.z, v1.w};

    float sum = 0.f;
#pragma unroll
    for (int i = 0; i < 8; ++i) sum += vals[i];
#pragma unroll
    for (int off = 32; off > 0; off >>= 1) sum += __shfl_xor(sum, off);
    float mean = sum * (1.0f / 512.0f);

    float var = 0.f;
#pragma unroll
    for (int i = 0; i < 8; ++i) {
        float d = vals[i] - mean;
        var += d * d;
    }
#pragma unroll
    for (int off = 32; off > 0; off >>= 1) var += __shfl_xor(var, off);
    var *= (1.0f / 512.0f);
    float rs = rsqrtf(var + 1e-5f);

    float4 g0 = *reinterpret_cast<const float4*>(g + lane * 8);
    float4 g1 = *reinterpret_cast<const float4*>(g + lane * 8 + 4);
    float4 b0 = *reinterpret_cast<const float4*>(beta + lane * 8);
    float4 b1 = *reinterpret_cast<const float4*>(beta + lane * 8 + 4);
    const float* gp0 = &g0.x; const float* gp1 = &g1.x;
    const float* bp0 = &b0.x; const float* bp1 = &b1.x;

    float4 o0, o1;
    float* q0 = &o0.x; float* q1 = &o1.x;
#pragma unroll
    for (int i = 0; i < 4; ++i) {
        q0[i] = (vals[i] - mean) * rs * gp0[i] + bp0[i];
        q1[i] = (vals[4 + i] - mean) * rs * gp1[i] + bp1[i];
    }
    float* orow = out + (size_t)row * CHS + lane * 8;
    *reinterpret_cast<float4*>(orow) = o0;
    *reinterpret_cast<float4*>(orow + 4) = o1;
}

// ---------------------------------------------------------------------------
// Outputs: glob (B,512) then gents (B,N,512), concatenated flat.
// ---------------------------------------------------------------------------
__global__ __launch_bounds__(256) void write_out_kernel(
    const float* __restrict__ vg, float* __restrict__ out)
{
    int i = blockIdx.x * 256 + threadIdx.x;       // float4 index over gents
    float4 v = reinterpret_cast<const float4*>(vg)[i];
    reinterpret_cast<float4*>(out + 2048)[i] = v;
    if (i < 512) {                                 // glob: 2048 floats
        int b = i >> 7;
        int c4 = i & 127;
        reinterpret_cast<float4*>(out)[i] =
            reinterpret_cast<const float4*>(vg)[((size_t)(b * CN + CE) * CHS) / 4 + c4];
    }
}

// ---------------------------------------------------------------------------
// Workspace layout (6 x 16 MB = 96 MB):
//   s0: vg, later t (vg is dead after the QKV GEMMs)
//   s1..s4: q,k,v,o; later the contiguous 64 MB h buffer (all dead by then)
//   s5: f
// ---------------------------------------------------------------------------
extern "C" void kernel_launch(void* const* d_in, const int* in_sizes, int n_in,
                              void* d_out, int out_size, void* d_ws, size_t ws_size,
                              hipStream_t stream)
{
    (void)in_sizes; (void)n_in; (void)out_size; (void)ws_size;

    const int*   adj    = (const int*)d_in[0];
    const int*   rels   = (const int*)d_in[1];
    const float* vents  = (const float*)d_in[2];
    const float* renc_w = (const float*)d_in[3];
    const float* Wq     = (const float*)d_in[4];
    const float* bq     = (const float*)d_in[5];
    const float* Wk     = (const float*)d_in[6];
    const float* bk     = (const float*)d_in[7];
    const float* Wv     = (const float*)d_in[8];
    const float* bv     = (const float*)d_in[9];
    const float* Wo     = (const float*)d_in[10];
    const float* bo     = (const float*)d_in[11];
    const float* l1w    = (const float*)d_in[12];
    const float* l1b    = (const float*)d_in[13];
    const float* l2w    = (const float*)d_in[14];
    const float* l2b    = (const float*)d_in[15];
    const float* prelu  = (const float*)d_in[16];
    const float* lng    = (const float*)d_in[17];
    const float* lnb    = (const float*)d_in[18];

    float* ws = (float*)d_ws;
    const size_t M4 = (size_t)CM * CHS;   // 4,194,304 floats (16 MB)
    float* s0 = ws;                        // vg / t
    float* s1 = ws + 1 * M4;               // q / h[0]
    float* s2 = ws + 2 * M4;               // k / h[1]
    float* s3 = ws + 3 * M4;               // v / h[2]
    float* s4 = ws + 4 * M4;               // o / h[3]
    float* s5 = ws + 5 * M4;               // f

    build_vg_kernel<<<4096, 256, 0, stream>>>(vents, renc_w, rels, s0);

    for (int j = 0; j < 2; ++j) {
        const float* Wq_j = Wq + (size_t)j * CHS * CHS;
        const float* Wk_j = Wk + (size_t)j * CHS * CHS;
        const float* Wv_j = Wv + (size_t)j * CHS * CHS;
        const float* Wo_j = Wo + (size_t)j * CHS * CHS;
        const float* bq_j = bq + j * CHS;
        const float* bk_j = bk + j * CHS;
        const float* bv_j = bv + j * CHS;
        const float* bo_j = bo + j * CHS;
        const float* l1w_j = l1w + (size_t)j * CHS * 4 * CHS;
        const float* l1b_j = l1b + j * 4 * CHS;
        const float* l2w_j = l2w + (size_t)j * 4 * CHS * CHS;
        const float* l2b_j = l2b + j * CHS;
        const float* pr_j  = prelu + j * 4 * CHS;
        const float* g_j   = lng + j * CHS;
        const float* b_j   = lnb + j * CHS;

        dim3 g512(CHS / GBN, CM / GBM);            // (8, 64)
        gemm_bias_kernel<<<g512, 256, 0, stream>>>(s0, Wq_j, bq_j, nullptr, s1, CHS, CHS);
        gemm_bias_kernel<<<g512, 256, 0, stream>>>(s0, Wk_j, bk_j, nullptr, s2, CHS, CHS);
        gemm_bias_kernel<<<g512, 256, 0, stream>>>(s0, Wv_j, bv_j, nullptr, s3, CHS, CHS);

        attn_kernel<<<dim3(CN / ABQ, CNH, CB), 512, 0, stream>>>(s1, s2, s3, adj, s4);

        // o @ Wo + bo -> s1 ; t = LN(s1) -> s0 (vg dead from here on)
        gemm_bias_kernel<<<g512, 256, 0, stream>>>(s4, Wo_j, bo_j, nullptr, s1, CHS, CHS);
        ln_kernel<<<CM / 4, 256, 0, stream>>>(s1, nullptr, g_j, b_j, s0);

        // h = prelu(t @ l1w + l1b) -> s1..s4 (contiguous 64 MB)
        gemm_bias_kernel<<<dim3(4 * CHS / GBN, CM / GBM), 256, 0, stream>>>(
            s0, l1w_j, l1b_j, pr_j, s1, CHS, 4 * CHS);
        // f = h @ l2w + l2b -> s5
        gemm_bias_kernel<<<g512, 256, 0, stream>>>(s1, l2w_j, l2b_j, nullptr, s5, 4 * CHS, CHS);

        // vg = LN(f + t) -> s0
        ln_kernel<<<CM / 4, 256, 0, stream>>>(s5, s0, g_j, b_j, s0);
    }

    write_out_kernel<<<4096, 256, 0, stream>>>(s0, (float*)d_out);
}